// Round 10
// baseline (94.504 us; speedup 1.0000x reference)
//
#include <hip/hip_runtime.h>
#include <hip/hip_bf16.h>

#define NROWS 8192
#define DDIM  128
#define NKCH  64                    // n-chunks
#define CHN   (NROWS / NKCH)        // 128 n-rows per chunk
#define NPAIR 10                    // triangular (ti<=tj) over 4 a-groups of 64 dims
#define GB_BLOCKS 160               // gram_b grid (10*4096/256)
#define NBP   68                    // nbuf pitch in shorts (64 + 4 pad)

typedef unsigned short ushort_t;
typedef unsigned int   uint_t;
typedef __attribute__((ext_vector_type(8))) short short8;
typedef __attribute__((ext_vector_type(4))) float floatx4;

// round-to-nearest-even fp32 -> bf16 bits
static __device__ inline ushort_t f2bf(float f) {
    union { float f; uint_t u; } a; a.f = f;
    uint_t u = a.u + 0x7fffu + ((a.u >> 16) & 1u);
    return (ushort_t)(u >> 16);
}

// decode triangular pair p -> (ti,tj), ti<=tj over 4 groups
static __device__ inline void pair_decode(int p, int* ti, int* tj) {
    int i = 0, len = 4;
    while (p >= len) { p -= len; len--; i++; }
    *ti = i; *tj = i + p;
}

// K1: fused normalize + transpose + partial Gram. Block = (pair, n-chunk).
// Re-normalizes its own 128 n-rows from q/k (L2/L3-hot), transposes via LDS
// bounce buffer into the R7-verified XOR-swizzled panel layout, then runs the
// byte-identical R7 MFMA + P-write. No Gt intermediate, no norm launch.
__global__ __launch_bounds__(128, 2) void fused_gram_kernel(
    const float* __restrict__ q, const float* __restrict__ k,
    float* __restrict__ P, double* acc, uint_t* counter)
{
    __shared__ ushort_t nbuf[CHN * NBP];   // 17 KB: row-major normalized half-rows
    __shared__ ushort_t sA[64 * CHN];      // 16 KB: panel A (64 a x 128 n, swizzled)
    __shared__ ushort_t sB[64 * CHN];      // 16 KB: panel B

    if (blockIdx.x == 0 && threadIdx.x == 0) { *acc = 0.0; *counter = 0u; }

    int pair = blockIdx.x >> 6;         // 0..9
    int c    = blockIdx.x & 63;         // n-chunk
    int ti, tj;
    pair_decode(pair, &ti, &tj);

    int tid = threadIdx.x;
    int w   = tid >> 6;                 // wave 0/1
    int l   = tid & 63;
    int h   = l >> 5;                   // half-wave: row parity
    int li  = l & 31;                   // lane in half: 4 dims each

    // ---- build both panels (t = ti then tj) ----
    #pragma unroll
    for (int p = 0; p < 2; ++p) {
        int t = p ? tj : ti;
        const float* src = (t < 2) ? q : k;
        int half = t & 1;                            // dim half 0/1
        ushort_t* panel = p ? sB : sA;

        // normalize pass: 4 rows per iteration (2 waves x 2 half-waves)
        #pragma unroll
        for (int it = 0; it < 32; ++it) {
            int rl  = it * 4 + w * 2 + h;            // local n-row 0..127
            int row = c * CHN + rl;
            float4 v = ((const float4*)(src + (size_t)row * DDIM))[li];
            float ss = v.x * v.x + v.y * v.y + v.z * v.z + v.w * v.w;
            #pragma unroll
            for (int o = 16; o > 0; o >>= 1) ss += __shfl_xor(ss, o, 64);
            float inv = rsqrtf(fmaxf(ss, 1e-16f));
            int col = 4 * li - 64 * half;            // short col in nbuf
            if (col >= 0 && col < 64) {
                uint2 p2;
                p2.x = (uint_t)f2bf(v.x * inv) | ((uint_t)f2bf(v.y * inv) << 16);
                p2.y = (uint_t)f2bf(v.z * inv) | ((uint_t)f2bf(v.w * inv) << 16);
                *(uint2*)&nbuf[rl * NBP + col] = p2;
            }
        }
        __syncthreads();

        // transpose gather: thread owns column a = tid&63, n-segment tid>>6
        int a   = tid & 63;
        int seg = tid >> 6;                          // 0/1: chunks seg*8..seg*8+7
        #pragma unroll
        for (int cl = 0; cl < 8; ++cl) {
            int ch = seg * 8 + cl;                   // logical 16B chunk: n=ch*8..+7
            union { ushort_t u16[8]; uint4 v; } tmp;
            #pragma unroll
            for (int e = 0; e < 8; ++e)
                tmp.u16[e] = nbuf[(ch * 8 + e) * NBP + a];
            int slot = ch ^ (a & 7);                 // XOR swizzle (R7 layout)
            *(uint4*)&panel[a * CHN + slot * 8] = tmp.v;
        }
        __syncthreads();
    }

    // ---- MFMA part: byte-identical to R7 gram_a ----
    int m    = l & 15;
    int quad = l >> 4;

    floatx4 accC[2][4];
    #pragma unroll
    for (int at = 0; at < 2; ++at)
        #pragma unroll
        for (int bt = 0; bt < 4; ++bt)
            accC[at][bt] = (floatx4){0.f, 0.f, 0.f, 0.f};

    #pragma unroll
    for (int kp = 0; kp < 4; ++kp) {
        short8 af[2], bf[4];
        #pragma unroll
        for (int at = 0; at < 2; ++at) {
            int ra   = w * 32 + at * 16 + m;
            int phys = (kp * 4 + quad) ^ (ra & 7);
            af[at] = *(const short8*)&sA[ra * CHN + phys * 8];
        }
        #pragma unroll
        for (int bt = 0; bt < 4; ++bt) {
            int rb   = bt * 16 + m;
            int phys = (kp * 4 + quad) ^ (rb & 7);
            bf[bt] = *(const short8*)&sB[rb * CHN + phys * 8];
        }
        #pragma unroll
        for (int at = 0; at < 2; ++at)
            #pragma unroll
            for (int bt = 0; bt < 4; ++bt)
                accC[at][bt] = __builtin_amdgcn_mfma_f32_16x16x32_bf16(af[at], bf[bt], accC[at][bt], 0, 0, 0);
    }

    // write 64x64 fp32 partial (C layout: col=m, row=quad*4+reg)
    float* pt = P + ((size_t)pair * NKCH + c) * 4096;
    #pragma unroll
    for (int at = 0; at < 2; ++at)
        #pragma unroll
        for (int bt = 0; bt < 4; ++bt)
            #pragma unroll
            for (int r = 0; r < 4; ++r) {
                int row = w * 32 + at * 16 + quad * 4 + r;
                int col = bt * 16 + m;
                pt[row * 64 + col] = accC[at][bt][r];
            }
}

// K2: reduce partials over 64 chunks, weight (sign x symmetry), square,
// fp64 accumulate; LAST block finalizes into out. (R7-proven version.)
__global__ __launch_bounds__(256) void gram_b_kernel(
    const float* __restrict__ P, double* acc, uint_t* counter, float* out)
{
    __shared__ float wsum[4];
    int e    = blockIdx.x * 256 + threadIdx.x;   // 0..40959
    int pair = e >> 12;
    int idx  = e & 4095;

    float s = 0.f;
    #pragma unroll
    for (int c = 0; c < NKCH; ++c)
        s += P[((size_t)pair * NKCH + c) * 4096 + idx];

    int ti, tj;
    pair_decode(pair, &ti, &tj);
    float wgt = ((ti < 2) == (tj < 2)) ? 1.f : -1.f;
    if (ti != tj) wgt *= 2.f;                    // symmetric tile counted twice
    float v = wgt * s * s;

    int w = threadIdx.x >> 6, l = threadIdx.x & 63;
    #pragma unroll
    for (int o = 32; o > 0; o >>= 1) v += __shfl_xor(v, o, 64);
    if (l == 0) wsum[w] = v;
    __syncthreads();
    if (threadIdx.x == 0) {
        double t = (double)wsum[0] + (double)wsum[1] + (double)wsum[2] + (double)wsum[3];
        atomicAdd(acc, t);
        __threadfence();
        uint_t old = atomicAdd(counter, 1u);
        if (old == GB_BLOCKS - 1) {
            double total = atomicAdd(acc, 0.0);  // coherent read of final sum
            out[0] = (float)(total * (1.0 / ((double)NROWS * (double)(NROWS - 1))));
        }
    }
}

extern "C" void kernel_launch(void* const* d_in, const int* in_sizes, int n_in,
                              void* d_out, int out_size, void* d_ws, size_t ws_size,
                              hipStream_t stream) {
    const float* q = (const float*)d_in[0];
    const float* k = (const float*)d_in[1];
    float* out = (float*)d_out;

    double* acc = (double*)d_ws;
    uint_t* cnt = (uint_t*)((char*)d_ws + 64);
    float*  P   = (float*)((char*)d_ws + 256);   // 10 x 64 x 4096 fp32 = 10 MB

    fused_gram_kernel<<<NPAIR * NKCH, 128, 0, stream>>>(q, k, P, acc, cnt);
    gram_b_kernel<<<GB_BLOCKS, 256, 0, stream>>>(P, acc, cnt, out);
}

// Round 11
// 73.823 us; speedup vs baseline: 1.2802x; 1.2802x over previous
//
#include <hip/hip_runtime.h>
#include <hip/hip_bf16.h>

#define NROWS 8192
#define DDIM  128
#define NKCH  64                    // n-chunks
#define CHN   128                   // n per chunk
#define NPAIR 10                    // triangular (ti<=tj) over 4 dim-groups of 64
#define GB_BLOCKS 160               // gram_b grid (10*4096/256)
#define NPAD  38                    // norm LDS column-major pitch in shorts

typedef unsigned short ushort_t;
typedef unsigned int   uint_t;
typedef __attribute__((ext_vector_type(8))) short short8;
typedef __attribute__((ext_vector_type(4))) float floatx4;

#define LDS_PTR(p) ((__attribute__((address_space(3))) void*)(p))
#define GLB_PTR(p) ((const __attribute__((address_space(1))) void*)(p))

// round-to-nearest-even fp32 -> bf16 bits
static __device__ inline ushort_t f2bf(float f) {
    union { float f; uint_t u; } a; a.f = f;
    uint_t u = a.u + 0x7fffu + ((a.u >> 16) & 1u);
    return (ushort_t)(u >> 16);
}

// decode triangular pair p -> (ti,tj), ti<=tj over 4 groups
static __device__ inline void pair_decode(int p, int* ti, int* tj) {
    int i = 0, len = 4;
    while (p >= len) { p -= len; len--; i++; }
    *ti = i; *tj = i + p;
}

// K1: row-normalize q,k -> bf16, write BLOCKED transposed Gt:
// layout [c:64][dim:256][n:128], dim<128 = Qn, dim>=128 = Kn.
// 256 blocks x 32 n-rows. Transpose via column-major LDS: scalar u16 WRITES
// (no latency chain), vectorized b32 reads + contiguous dwordx4 global stores.
__global__ __launch_bounds__(256) void norm_t_kernel(
    const float* __restrict__ q, const float* __restrict__ k,
    ushort_t* __restrict__ Gt, double* acc, uint_t* counter)
{
    __shared__ ushort_t lds[256 * NPAD];   // 19 KB: [dim][n-local]
    if (blockIdx.x == 0 && threadIdx.x == 0) { *acc = 0.0; *counter = 0u; }

    int b   = blockIdx.x;        // 256 blocks x 32 rows
    int c   = b >> 2;            // chunk 0..63
    int sub = b & 3;             // 32-row quarter of the chunk
    int w   = threadIdx.x >> 6;
    int l   = threadIdx.x & 63;
    int h   = l >> 5;            // half-wave: row parity
    int li  = l & 31;            // lane in half: 4 dims each

    #pragma unroll
    for (int i = 0; i < 4; ++i) {
        int rl  = i * 8 + w * 2 + h;             // local n-row 0..31
        int row = b * 32 + rl;
        {
            float4 v = ((const float4*)(q + (size_t)row * DDIM))[li];
            float ss = v.x * v.x + v.y * v.y + v.z * v.z + v.w * v.w;
            #pragma unroll
            for (int o = 16; o > 0; o >>= 1) ss += __shfl_xor(ss, o, 64);
            float inv = rsqrtf(fmaxf(ss, 1e-16f));
            lds[(4 * li + 0) * NPAD + rl] = f2bf(v.x * inv);
            lds[(4 * li + 1) * NPAD + rl] = f2bf(v.y * inv);
            lds[(4 * li + 2) * NPAD + rl] = f2bf(v.z * inv);
            lds[(4 * li + 3) * NPAD + rl] = f2bf(v.w * inv);
        }
        {
            float4 v = ((const float4*)(k + (size_t)row * DDIM))[li];
            float ss = v.x * v.x + v.y * v.y + v.z * v.z + v.w * v.w;
            #pragma unroll
            for (int o = 16; o > 0; o >>= 1) ss += __shfl_xor(ss, o, 64);
            float inv = rsqrtf(fmaxf(ss, 1e-16f));
            lds[(128 + 4 * li + 0) * NPAD + rl] = f2bf(v.x * inv);
            lds[(128 + 4 * li + 1) * NPAD + rl] = f2bf(v.y * inv);
            lds[(128 + 4 * li + 2) * NPAD + rl] = f2bf(v.z * inv);
            lds[(128 + 4 * li + 3) * NPAD + rl] = f2bf(v.w * inv);
        }
    }
    __syncthreads();

    // phase 2: thread owns dim a; vector-read its 32 n (16 x b32, 4B-aligned
    // since NPAD even), store 64 B contiguous into blocked Gt.
    int a = threadIdx.x;
    union { uint_t u32[16]; uint4 v4[4]; } tb;
    #pragma unroll
    for (int t = 0; t < 16; ++t)
        tb.u32[t] = *(const uint_t*)&lds[a * NPAD + 2 * t];

    char* gdst = (char*)Gt + (size_t)(c * 256 + a) * (CHN * 2) + sub * 64;
    #pragma unroll
    for (int g = 0; g < 4; ++g)
        *(uint4*)(gdst + g * 16) = tb.v4[g];
}

// K2: partial Gram (R7-verified MFMA body). 10 symmetric tiles x 64 n-chunks
// = 640 blocks, 128 threads, 32 KB LDS. Blocked Gt makes each panel one
// CONTIGUOUS 16 KB stream for global_load_lds (XOR-chunk swizzle on source).
__global__ __launch_bounds__(128, 2) void gram_a_kernel(
    const ushort_t* __restrict__ Gt, float* __restrict__ P)
{
    __shared__ ushort_t sA[64 * CHN];   // 16 KB
    __shared__ ushort_t sB[64 * CHN];   // 16 KB

    int pair = blockIdx.x >> 6;         // 0..9
    int c    = blockIdx.x & 63;         // n-chunk
    int ti, tj;
    pair_decode(pair, &ti, &tj);
    int tid = threadIdx.x;

    const char* gA = (const char*)Gt + (size_t)(c * 256 + ti * 64) * (CHN * 2);
    const char* gB = (const char*)Gt + (size_t)(c * 256 + tj * 64) * (CHN * 2);

    #pragma unroll
    for (int it = 0; it < 8; ++it) {
        int ch = it * 128 + tid;               // 0..1023
        int row = ch >> 4, phys = ch & 15;
        int logical = phys ^ (row & 7);
        __builtin_amdgcn_global_load_lds(GLB_PTR(gA + row * 256 + logical * 16),
                                         LDS_PTR((char*)sA + ch * 16), 16, 0, 0);
    }
    #pragma unroll
    for (int it = 0; it < 8; ++it) {
        int ch = it * 128 + tid;
        int row = ch >> 4, phys = ch & 15;
        int logical = phys ^ (row & 7);
        __builtin_amdgcn_global_load_lds(GLB_PTR(gB + row * 256 + logical * 16),
                                         LDS_PTR((char*)sB + ch * 16), 16, 0, 0);
    }
    __syncthreads();

    int w    = tid >> 6;        // a-strip: rows w*32..w*32+31
    int l    = tid & 63;
    int m    = l & 15;
    int quad = l >> 4;

    floatx4 accC[2][4];
    #pragma unroll
    for (int at = 0; at < 2; ++at)
        #pragma unroll
        for (int bt = 0; bt < 4; ++bt)
            accC[at][bt] = (floatx4){0.f, 0.f, 0.f, 0.f};

    #pragma unroll
    for (int kp = 0; kp < 4; ++kp) {
        short8 af[2], bf[4];
        #pragma unroll
        for (int at = 0; at < 2; ++at) {
            int ra   = w * 32 + at * 16 + m;
            int phys = (kp * 4 + quad) ^ (ra & 7);
            af[at] = *(const short8*)&sA[ra * CHN + phys * 8];
        }
        #pragma unroll
        for (int bt = 0; bt < 4; ++bt) {
            int rb   = bt * 16 + m;
            int phys = (kp * 4 + quad) ^ (rb & 7);
            bf[bt] = *(const short8*)&sB[rb * CHN + phys * 8];
        }
        #pragma unroll
        for (int at = 0; at < 2; ++at)
            #pragma unroll
            for (int bt = 0; bt < 4; ++bt)
                accC[at][bt] = __builtin_amdgcn_mfma_f32_16x16x32_bf16(af[at], bf[bt], accC[at][bt], 0, 0, 0);
    }

    // write 64x64 fp32 partial (C layout: col=m, row=quad*4+reg)
    float* pt = P + ((size_t)pair * NKCH + c) * 4096;
    #pragma unroll
    for (int at = 0; at < 2; ++at)
        #pragma unroll
        for (int bt = 0; bt < 4; ++bt)
            #pragma unroll
            for (int r = 0; r < 4; ++r) {
                int row = w * 32 + at * 16 + quad * 4 + r;
                int col = bt * 16 + m;
                pt[row * 64 + col] = accC[at][bt][r];
            }
}

// K3: reduce partials over 64 chunks, weight (sign x symmetry), square,
// fp64 accumulate; LAST block finalizes into out. (R7-proven version.)
__global__ __launch_bounds__(256) void gram_b_kernel(
    const float* __restrict__ P, double* acc, uint_t* counter, float* out)
{
    __shared__ float wsum[4];
    int e    = blockIdx.x * 256 + threadIdx.x;   // 0..40959
    int pair = e >> 12;
    int idx  = e & 4095;

    float s = 0.f;
    #pragma unroll
    for (int c = 0; c < NKCH; ++c)
        s += P[((size_t)pair * NKCH + c) * 4096 + idx];

    int ti, tj;
    pair_decode(pair, &ti, &tj);
    float wgt = ((ti < 2) == (tj < 2)) ? 1.f : -1.f;
    if (ti != tj) wgt *= 2.f;                    // symmetric tile counted twice
    float v = wgt * s * s;

    int w = threadIdx.x >> 6, l = threadIdx.x & 63;
    #pragma unroll
    for (int o = 32; o > 0; o >>= 1) v += __shfl_xor(v, o, 64);
    if (l == 0) wsum[w] = v;
    __syncthreads();
    if (threadIdx.x == 0) {
        double t = (double)wsum[0] + (double)wsum[1] + (double)wsum[2] + (double)wsum[3];
        atomicAdd(acc, t);
        __threadfence();
        uint_t old = atomicAdd(counter, 1u);
        if (old == GB_BLOCKS - 1) {
            double total = atomicAdd(acc, 0.0);  // coherent read of final sum
            out[0] = (float)(total * (1.0 / ((double)NROWS * (double)(NROWS - 1))));
        }
    }
}

extern "C" void kernel_launch(void* const* d_in, const int* in_sizes, int n_in,
                              void* d_out, int out_size, void* d_ws, size_t ws_size,
                              hipStream_t stream) {
    const float* q = (const float*)d_in[0];
    const float* k = (const float*)d_in[1];
    float* out = (float*)d_out;

    double*   acc = (double*)d_ws;
    uint_t*   cnt = (uint_t*)((char*)d_ws + 64);
    ushort_t* Gt  = (ushort_t*)((char*)d_ws + 256);                    // 4 MB blocked
    float*    P   = (float*)((char*)d_ws + 256 + (size_t)NKCH * 256 * CHN * 2); // 10 MB

    norm_t_kernel<<<NROWS / 32, 256, 0, stream>>>(q, k, Gt, acc, cnt);
    gram_a_kernel<<<NPAIR * NKCH, 128, 0, stream>>>(Gt, P);
    gram_b_kernel<<<GB_BLOCKS, 256, 0, stream>>>(P, acc, cnt, out);
}